// Round 1
// baseline (225.175 us; speedup 1.0000x reference)
//
#include <hip/hip_runtime.h>
#include <hip/hip_bf16.h>
#include <math.h>

typedef __bf16 bf16;
typedef bf16  bf16x8 __attribute__((ext_vector_type(8)));
typedef bf16  bf16x4 __attribute__((ext_vector_type(4)));
typedef float f32x4  __attribute__((ext_vector_type(4)));

#define B_   4
#define N_   2048
#define CH_  512
#define H_   8
#define D_   64
#define HID_ 512

__device__ __forceinline__ f32x4 mfma16(bf16x8 a, bf16x8 b, f32x4 c) {
    return __builtin_amdgcn_mfma_f32_16x16x32_bf16(a, b, c, 0, 0, 0);
}

// ---------------- rope table: cos/sin[pos][d/2], 2048 x 32 ----------------
__global__ void rope_table_k(float* __restrict__ cosT, float* __restrict__ sinT) {
    int idx = blockIdx.x * 256 + threadIdx.x;   // 65536 = 2048*32
    int pos = idx >> 5, fi = idx & 31;
    double inv = pow(10000.0, -(double)(2 * fi) / 64.0);
    double ang = (double)pos * inv;
    cosT[idx] = (float)cos(ang);
    sinT[idx] = (float)sin(ang);
}

// ---------------- QKV GEMM + scale + RoPE -> Qb/Kb/Vb bf16 [B][H][N][64] ----------------
__global__ __launch_bounds__(256) void qkv_rope_k(
    const float* __restrict__ x, const float* __restrict__ w,
    const float* __restrict__ cosT, const float* __restrict__ sinT,
    bf16* __restrict__ Qb, bf16* __restrict__ Kb, bf16* __restrict__ Vb)
{
    __shared__ __align__(16) bf16 Xs[128][40];   // +8 pad -> 2-way max bank conflict
    __shared__ __align__(16) bf16 Ws[128][40];
    const int tid = threadIdx.x, lane = tid & 63, wid = tid >> 6;
    const int wr = wid >> 1, wc = wid & 1;
    const int m0 = blockIdx.x * 128, n0 = blockIdx.y * 128;
    const int l15 = lane & 15, l4 = lane >> 4;
    const int sr = tid >> 1, sh = (tid & 1) * 16;

    f32x4 acc[4][4] = {};

    for (int kt = 0; kt < 16; ++kt) {
        __syncthreads();
        {
            const float4* xp = reinterpret_cast<const float4*>(x + (size_t)(m0 + sr) * CH_ + kt * 32 + sh);
            const float4* wp = reinterpret_cast<const float4*>(w + (size_t)(n0 + sr) * CH_ + kt * 32 + sh);
#pragma unroll
            for (int j = 0; j < 4; ++j) {
                float4 f = xp[j];
                bf16x4 o1 = { (bf16)f.x, (bf16)f.y, (bf16)f.z, (bf16)f.w };
                *reinterpret_cast<bf16x4*>(&Xs[sr][sh + j * 4]) = o1;
                float4 g = wp[j];
                bf16x4 o2 = { (bf16)g.x, (bf16)g.y, (bf16)g.z, (bf16)g.w };
                *reinterpret_cast<bf16x4*>(&Ws[sr][sh + j * 4]) = o2;
            }
        }
        __syncthreads();
        bf16x8 a[4], bb[4];
#pragma unroll
        for (int mf = 0; mf < 4; ++mf)
            a[mf] = *reinterpret_cast<const bf16x8*>(&Xs[wr * 64 + mf * 16 + l15][l4 * 8]);
#pragma unroll
        for (int nf = 0; nf < 4; ++nf)
            bb[nf] = *reinterpret_cast<const bf16x8*>(&Ws[wc * 64 + nf * 16 + l15][l4 * 8]);
#pragma unroll
        for (int mf = 0; mf < 4; ++mf)
#pragma unroll
            for (int nf = 0; nf < 4; ++nf)
                acc[mf][nf] = mfma16(a[mf], bb[nf], acc[mf][nf]);
    }

    // epilogue: C[row][col]; col -> (sec, head, d); RoPE pairs are adjacent lanes
#pragma unroll
    for (int nf = 0; nf < 4; ++nf) {
        const int col = n0 + wc * 64 + nf * 16 + l15;
        const int sec = col >> 9;            // 0=Q 1=K 2=V (uniform per block-col)
        const int cc = col & 511;
        const int hh = cc >> 6, dd = cc & 63;
        const float sgn = (dd & 1) ? 1.f : -1.f;
#pragma unroll
        for (int mf = 0; mf < 4; ++mf) {
#pragma unroll
            for (int i = 0; i < 4; ++i) {
                const int row = m0 + wr * 64 + mf * 16 + l4 * 4 + i;
                const int bb_ = row >> 11, pos = row & 2047;
                const float v = acc[mf][nf][i];
                const float v2 = __shfl_xor(v, 1);   // partner d^1
                const size_t dst = ((size_t)((bb_ * H_ + hh) * N_ + pos)) * D_ + dd;
                if (sec == 2) {
                    Vb[dst] = (bf16)v;
                } else {
                    const float c = cosT[pos * 32 + (dd >> 1)];
                    const float s = sinT[pos * 32 + (dd >> 1)];
                    const float r = v * c + sgn * v2 * s;
                    if (sec == 0) Qb[dst] = (bf16)(r * 0.125f);
                    else          Kb[dst] = (bf16)r;
                }
            }
        }
    }
}

// ---------------- flash attention: block=(qt,h,b), 4 waves x 16 q-rows, K-blocks of 64 ----------------
__global__ __launch_bounds__(256) void attn_k(
    const bf16* __restrict__ Qb, const bf16* __restrict__ Kb, const bf16* __restrict__ Vb,
    const float* __restrict__ bias, bf16* __restrict__ AO)
{
    __shared__ __align__(16) bf16 Ks[64][72];      // row-major K tile
    __shared__ __align__(16) bf16 Vs[64][72];      // transposed V tile: Vs[d][k]
    __shared__ __align__(16) bf16 Pw[4][16][72];   // per-wave P
    const int tid = threadIdx.x, lane = tid & 63, wid = tid >> 6;
    const int l15 = lane & 15, l4 = lane >> 4;
    const int qt = blockIdx.x, h = blockIdx.y, b = blockIdx.z;
    const int q0 = qt * 64 + wid * 16;
    const size_t bh = (size_t)(b * H_ + h) * N_ * D_;

    bf16x8 qa[2];
#pragma unroll
    for (int ks = 0; ks < 2; ++ks)
        qa[ks] = *reinterpret_cast<const bf16x8*>(Qb + bh + (size_t)(q0 + l15) * D_ + ks * 32 + l4 * 8);

    f32x4 o[4] = {};
    float mrun[4], lrun[4];
#pragma unroll
    for (int i = 0; i < 4; ++i) { mrun[i] = -INFINITY; lrun[i] = 0.f; }

    const int sr = tid >> 2, sseg = (tid & 3) * 16;

    for (int kb = 0; kb < 32; ++kb) {
        __syncthreads();
        {   // stage K (row-major) and V (transposed)
            const bf16* kp = Kb + bh + (size_t)(kb * 64 + sr) * D_ + sseg;
            bf16x8 k0 = *reinterpret_cast<const bf16x8*>(kp);
            bf16x8 k1 = *reinterpret_cast<const bf16x8*>(kp + 8);
            *reinterpret_cast<bf16x8*>(&Ks[sr][sseg])     = k0;
            *reinterpret_cast<bf16x8*>(&Ks[sr][sseg + 8]) = k1;
            const bf16* vp = Vb + bh + (size_t)(kb * 64 + sr) * D_ + sseg;
            bf16x8 v0 = *reinterpret_cast<const bf16x8*>(vp);
            bf16x8 v1 = *reinterpret_cast<const bf16x8*>(vp + 8);
#pragma unroll
            for (int j = 0; j < 8; ++j) {
                Vs[sseg + j][sr]     = v0[j];
                Vs[sseg + 8 + j][sr] = v1[j];
            }
        }
        __syncthreads();

        f32x4 s[4] = {};
#pragma unroll
        for (int cf = 0; cf < 4; ++cf) {
#pragma unroll
            for (int ks = 0; ks < 2; ++ks) {
                bf16x8 kf = *reinterpret_cast<const bf16x8*>(&Ks[cf * 16 + l15][ks * 32 + l4 * 8]);
                s[cf] = mfma16(qa[ks], kf, s[cf]);
            }
        }
        // + bias
#pragma unroll
        for (int cf = 0; cf < 4; ++cf)
#pragma unroll
            for (int i = 0; i < 4; ++i)
                s[cf][i] += bias[((size_t)h * N_ + (q0 + l4 * 4 + i)) * N_ + kb * 64 + cf * 16 + l15];

        // online softmax (rows live across the 16-lane group)
        float pr[4][4], psum[4];
#pragma unroll
        for (int i = 0; i < 4; ++i) {
            float t = fmaxf(fmaxf(s[0][i], s[1][i]), fmaxf(s[2][i], s[3][i]));
#pragma unroll
            for (int msk = 1; msk <= 8; msk <<= 1) t = fmaxf(t, __shfl_xor(t, msk));
            const float mnew = fmaxf(mrun[i], t);
            const float scl = __expf(mrun[i] - mnew);
            mrun[i] = mnew;
            lrun[i] *= scl;
#pragma unroll
            for (int df = 0; df < 4; ++df) o[df][i] *= scl;
            float ps = 0.f;
#pragma unroll
            for (int cf = 0; cf < 4; ++cf) {
                const float p = __expf(s[cf][i] - mnew);
                pr[cf][i] = p;
                ps += p;
            }
            psum[i] = ps;
        }
#pragma unroll
        for (int cf = 0; cf < 4; ++cf)
#pragma unroll
            for (int i = 0; i < 4; ++i)
                Pw[wid][l4 * 4 + i][cf * 16 + l15] = (bf16)pr[cf][i];
#pragma unroll
        for (int i = 0; i < 4; ++i) {
            float ps = psum[i];
#pragma unroll
            for (int msk = 1; msk <= 8; msk <<= 1) ps += __shfl_xor(ps, msk);
            lrun[i] += ps;
        }
        // O += P @ V
#pragma unroll
        for (int ks = 0; ks < 2; ++ks) {
            bf16x8 pa = *reinterpret_cast<const bf16x8*>(&Pw[wid][l15][ks * 32 + l4 * 8]);
#pragma unroll
            for (int df = 0; df < 4; ++df) {
                bf16x8 vf = *reinterpret_cast<const bf16x8*>(&Vs[df * 16 + l15][ks * 32 + l4 * 8]);
                o[df] = mfma16(pa, vf, o[df]);
            }
        }
    }

#pragma unroll
    for (int df = 0; df < 4; ++df)
#pragma unroll
        for (int i = 0; i < 4; ++i) {
            const int row = q0 + l4 * 4 + i;
            const float val = o[df][i] / lrun[i];
            AO[((size_t)(b * N_ + row)) * HID_ + h * D_ + df * 16 + l15] = (bf16)val;
        }
}

// ---------------- out projection: AO(bf16) @ w_out^T -> f32 ----------------
__global__ __launch_bounds__(256) void proj_k(
    const bf16* __restrict__ A, const float* __restrict__ w, float* __restrict__ out)
{
    __shared__ __align__(16) bf16 As[128][40];
    __shared__ __align__(16) bf16 Ws[128][40];
    const int tid = threadIdx.x, lane = tid & 63, wid = tid >> 6;
    const int wr = wid >> 1, wc = wid & 1;
    const int m0 = blockIdx.x * 128, n0 = blockIdx.y * 128;
    const int l15 = lane & 15, l4 = lane >> 4;
    const int sr = tid >> 1, sh = (tid & 1) * 16;

    f32x4 acc[4][4] = {};

    for (int kt = 0; kt < 16; ++kt) {
        __syncthreads();
        {
            const bf16* ap = A + (size_t)(m0 + sr) * HID_ + kt * 32 + sh;
            *reinterpret_cast<bf16x8*>(&As[sr][sh])     = *reinterpret_cast<const bf16x8*>(ap);
            *reinterpret_cast<bf16x8*>(&As[sr][sh + 8]) = *reinterpret_cast<const bf16x8*>(ap + 8);
            const float4* wp = reinterpret_cast<const float4*>(w + (size_t)(n0 + sr) * HID_ + kt * 32 + sh);
#pragma unroll
            for (int j = 0; j < 4; ++j) {
                float4 g = wp[j];
                bf16x4 o2 = { (bf16)g.x, (bf16)g.y, (bf16)g.z, (bf16)g.w };
                *reinterpret_cast<bf16x4*>(&Ws[sr][sh + j * 4]) = o2;
            }
        }
        __syncthreads();
        bf16x8 a[4], bb[4];
#pragma unroll
        for (int mf = 0; mf < 4; ++mf)
            a[mf] = *reinterpret_cast<const bf16x8*>(&As[wr * 64 + mf * 16 + l15][l4 * 8]);
#pragma unroll
        for (int nf = 0; nf < 4; ++nf)
            bb[nf] = *reinterpret_cast<const bf16x8*>(&Ws[wc * 64 + nf * 16 + l15][l4 * 8]);
#pragma unroll
        for (int mf = 0; mf < 4; ++mf)
#pragma unroll
            for (int nf = 0; nf < 4; ++nf)
                acc[mf][nf] = mfma16(a[mf], bb[nf], acc[mf][nf]);
    }
#pragma unroll
    for (int nf = 0; nf < 4; ++nf) {
        const int col = n0 + wc * 64 + nf * 16 + l15;
#pragma unroll
        for (int mf = 0; mf < 4; ++mf) {
#pragma unroll
            for (int i = 0; i < 4; ++i) {
                const int row = m0 + wr * 64 + mf * 16 + l4 * 4 + i;
                out[(size_t)row * HID_ + col] = acc[mf][nf][i];
            }
        }
    }
}

extern "C" void kernel_launch(void* const* d_in, const int* in_sizes, int n_in,
                              void* d_out, int out_size, void* d_ws, size_t ws_size,
                              hipStream_t stream) {
    (void)in_sizes; (void)n_in; (void)out_size; (void)ws_size;
    const float* x     = (const float*)d_in[0];
    const float* bias  = (const float*)d_in[1];
    const float* w_qkv = (const float*)d_in[2];
    const float* w_out = (const float*)d_in[3];
    float* out = (float*)d_out;

    bf16* Qb = (bf16*)d_ws;                 // [4][8][2048][64]
    bf16* Kb = Qb + 4194304;
    bf16* Vb = Kb + 4194304;
    bf16* AO = Vb + 4194304;                // [4][2048][512]
    float* cosT = (float*)(AO + 4194304);   // [2048][32]
    float* sinT = cosT + 65536;

    rope_table_k<<<dim3(256), 256, 0, stream>>>(cosT, sinT);
    qkv_rope_k  <<<dim3(64, 12), 256, 0, stream>>>(x, w_qkv, cosT, sinT, Qb, Kb, Vb);
    attn_k      <<<dim3(32, 8, 4), 256, 0, stream>>>(Qb, Kb, Vb, bias, AO);
    proj_k      <<<dim3(64, 4), 256, 0, stream>>>(AO, w_out, out);
}